// Round 1
// baseline (191.913 us; speedup 1.0000x reference)
//
#include <hip/hip_runtime.h>

#define BATCH 4
#define NPTS 16384
#define NQ 2048
#define NFEAT 64
#define NS 32
#define NCH 67  // 3 + NFEAT

// ---------------------------------------------------------------------------
// Kernel 1: transpose features (B, C, N) -> (B, N, C) so per-sample gathers
// are contiguous 256 B rows instead of 32 scattered 4 B column reads.
// ---------------------------------------------------------------------------
__global__ __launch_bounds__(256) void transpose_feat(
    const float* __restrict__ in, float* __restrict__ out) {
  __shared__ float tile[32][33];  // +1 pad: no bank conflicts
  const int b  = blockIdx.z;
  const int n0 = blockIdx.x * 32;
  const int c0 = blockIdx.y * 32;
  const int tx = threadIdx.x;  // 0..31
  const int ty = threadIdx.y;  // 0..7
  const float* inb  = in  + (size_t)b * NFEAT * NPTS;
  float*       outb = out + (size_t)b * NPTS * NFEAT;
#pragma unroll
  for (int i = 0; i < 32; i += 8) {
    tile[ty + i][tx] = inb[(size_t)(c0 + ty + i) * NPTS + (n0 + tx)];
  }
  __syncthreads();
#pragma unroll
  for (int i = 0; i < 32; i += 8) {
    outb[(size_t)(n0 + ty + i) * NFEAT + (c0 + tx)] = tile[tx][ty + i];
  }
}

// ---------------------------------------------------------------------------
// Kernel 2: fused ball-query + group. One 64-lane wave per query point.
// Query phase: scan 64 candidates/iter, ballot+prefix-popcount appends the
// hit indices in ascending order into a 32-slot LDS list; early exit at 32.
// Group phase: lane = (half, k); half-wave writes one channel's 32
// contiguous floats per iteration.
// ---------------------------------------------------------------------------
template <bool TRANS>
__global__ __launch_bounds__(256) void query_group(
    const float* __restrict__ xyz, const float* __restrict__ new_xyz,
    const float* __restrict__ feat, float* __restrict__ out) {
  __shared__ int sidx[4][NS];

  const int w    = threadIdx.x >> 6;
  const int lane = threadIdx.x & 63;
  const int query = blockIdx.x * 4 + w;
  const int b = query / NQ;
  const int j = query % NQ;

  const float* q = new_xyz + ((size_t)b * NQ + j) * 3;
  const float qx = q[0], qy = q[1], qz = q[2];
  const float* xb = xyz + (size_t)b * NPTS * 3;

  // Reference: mask = d2 < float(0.1*0.1). NOTE: (float)(0.1*0.1) ==
  // 0x3C23D70A which is NOT equal to 0.1f*0.1f (0x3C23D70B) — must match np.
  const float R2 = (float)(0.1 * 0.1);

  int count = 0;
  for (int base = 0; base < NPTS; base += 64) {
    const int i = base + lane;
    const float px = xb[i * 3 + 0];
    const float py = xb[i * 3 + 1];
    const float pz = xb[i * 3 + 2];
    // Match np exactly: no FMA contraction, sum order (dx^2 + dy^2) + dz^2.
    const float dx = __fsub_rn(qx, px);
    const float dy = __fsub_rn(qy, py);
    const float dz = __fsub_rn(qz, pz);
    const float d2 =
        __fadd_rn(__fadd_rn(__fmul_rn(dx, dx), __fmul_rn(dy, dy)),
                  __fmul_rn(dz, dz));
    const bool hit = d2 < R2;
    const unsigned long long m = __ballot(hit);
    if (hit) {
      const int pos = count + (int)__popcll(m & ((1ull << lane) - 1ull));
      if (pos < NS) sidx[w][pos] = i;
    }
    count += (int)__popcll(m);
    if (count >= NS) break;  // uniform across the wave
  }
  const int found = count < NS ? count : NS;

  // Pad: slots [found, 32) get the first hit index; all-zero if no hits.
  const int s0 = sidx[w][0];  // garbage if found==0, but then unused
  const int fill = (found > 0) ? s0 : 0;
  if (lane < NS && lane >= found) sidx[w][lane] = fill;

  // -------- group phase --------
  const int k = lane & 31;
  const int half = lane >> 5;
  const int gi = sidx[w][k];

  const float* pt = xb + (size_t)gi * 3;
  const float px = pt[0], py = pt[1], pz = pt[2];

  // out[((b*NCH + c)*NQ + j)*NS + k]
  const size_t obase = ((size_t)b * NCH * NQ + j) * (size_t)NS + k;
  for (int c = half; c < NCH; c += 2) {
    float v;
    if (c < 3) {
      v = (c == 0) ? __fsub_rn(px, qx)
                   : (c == 1) ? __fsub_rn(py, qy) : __fsub_rn(pz, qz);
    } else {
      if (TRANS)
        v = feat[((size_t)b * NPTS + gi) * NFEAT + (c - 3)];
      else
        v = feat[((size_t)b * NFEAT + (c - 3)) * NPTS + gi];
    }
    out[obase + (size_t)c * (NQ * NS)] = v;
  }
}

extern "C" void kernel_launch(void* const* d_in, const int* in_sizes, int n_in,
                              void* d_out, int out_size, void* d_ws,
                              size_t ws_size, hipStream_t stream) {
  const float* xyz     = (const float*)d_in[0];  // (B, N, 3)
  const float* new_xyz = (const float*)d_in[1];  // (B, NPOINT, 3)
  const float* feat    = (const float*)d_in[2];  // (B, C, N)
  float* out = (float*)d_out;                    // (B, 67, NPOINT, 32)

  const size_t need = (size_t)BATCH * NPTS * NFEAT * sizeof(float);
  const int nblocks = (BATCH * NQ) / 4;  // 4 waves (queries) per 256-thr block

  if (ws_size >= need) {
    float* featT = (float*)d_ws;  // (B, N, C)
    dim3 tg(NPTS / 32, NFEAT / 32, BATCH);
    dim3 tb(32, 8);
    transpose_feat<<<tg, tb, 0, stream>>>(feat, featT);
    query_group<true><<<nblocks, 256, 0, stream>>>(xyz, new_xyz, featT, out);
  } else {
    query_group<false><<<nblocks, 256, 0, stream>>>(xyz, new_xyz, feat, out);
  }
}

// Round 2
// 154.145 us; speedup vs baseline: 1.2450x; 1.2450x over previous
//
#include <hip/hip_runtime.h>

#define BATCH 4
#define NPTS 16384
#define NQ 2048
#define NFEAT 64
#define NS 32
#define NCH 67        // 3 + NFEAT
#define GRID 10       // cell edge 0.1 == radius
#define NCELL 1000
#define CSTRIDE 1024  // per-batch stride for cellStart
#define MAXHIT 128    // LDS hit-list capacity per query

__device__ __forceinline__ int prefix_popc(unsigned long long m) {
  return (int)__builtin_amdgcn_mbcnt_hi(
      (unsigned)(m >> 32), __builtin_amdgcn_mbcnt_lo((unsigned)m, 0u));
}

__device__ __forceinline__ void cell3(float x, float y, float z, int& cx,
                                      int& cy, int& cz) {
  cx = min(max((int)(x * 10.0f), 0), GRID - 1);
  cy = min(max((int)(y * 10.0f), 0), GRID - 1);
  cz = min(max((int)(z * 10.0f), 0), GRID - 1);
}

// ---------------------------------------------------------------------------
// Grid build
// ---------------------------------------------------------------------------
__global__ __launch_bounds__(256) void hist_kernel(
    const float* __restrict__ xyz, int* __restrict__ hist) {
  const int t = blockIdx.x * 256 + threadIdx.x;  // 0 .. B*N-1
  const int b = t / NPTS;
  const float x = xyz[(size_t)t * 3 + 0];
  const float y = xyz[(size_t)t * 3 + 1];
  const float z = xyz[(size_t)t * 3 + 2];
  int cx, cy, cz;
  cell3(x, y, z, cx, cy, cz);
  atomicAdd(&hist[b * NCELL + ((cz * GRID + cy) * GRID + cx)], 1);
}

__global__ __launch_bounds__(256) void scan_kernel(
    const int* __restrict__ hist, int* __restrict__ cellStart) {
  const int b = blockIdx.x;
  const int t = threadIdx.x;
  __shared__ int part[256];
  int loc[4];
  int s = 0;
#pragma unroll
  for (int r = 0; r < 4; r++) {
    const int c = t * 4 + r;
    const int v = (c < NCELL) ? hist[b * NCELL + c] : 0;
    loc[r] = s;
    s += v;
  }
  part[t] = s;
  __syncthreads();
  for (int d = 1; d < 256; d <<= 1) {
    const int v = (t >= d) ? part[t - d] : 0;
    __syncthreads();
    part[t] += v;
    __syncthreads();
  }
  const int excl = part[t] - s;  // exclusive prefix of this thread's chunk
#pragma unroll
  for (int r = 0; r < 4; r++) {
    const int c = t * 4 + r;
    if (c < NCELL) cellStart[b * CSTRIDE + c] = excl + loc[r];
  }
  if (t == 255) cellStart[b * CSTRIDE + NCELL] = part[255];  // total = NPTS
}

__global__ __launch_bounds__(256) void scatter_kernel(
    const float* __restrict__ xyz, const int* __restrict__ cellStart,
    int* __restrict__ fill, float4* __restrict__ cellPts) {
  const int t = blockIdx.x * 256 + threadIdx.x;
  const int b = t / NPTS;
  const int i = t % NPTS;
  const float x = xyz[(size_t)t * 3 + 0];
  const float y = xyz[(size_t)t * 3 + 1];
  const float z = xyz[(size_t)t * 3 + 2];
  int cx, cy, cz;
  cell3(x, y, z, cx, cy, cz);
  const int cid = (cz * GRID + cy) * GRID + cx;
  const int pos = cellStart[b * CSTRIDE + cid] + atomicAdd(&fill[b * NCELL + cid], 1);
  cellPts[b * NPTS + pos] = make_float4(x, y, z, __int_as_float(i));
}

// ---------------------------------------------------------------------------
// Transpose features (B, C, N) -> (B, N, C), 64x64 tiles, float4 both sides.
// ---------------------------------------------------------------------------
__global__ __launch_bounds__(256) void transpose_feat(
    const float* __restrict__ in, float* __restrict__ out) {
  __shared__ float tile[64][65];
  const int b = blockIdx.y;
  const int n0 = blockIdx.x * 64;
  const int t = threadIdx.x;
  const float* inb = in + (size_t)b * NFEAT * NPTS;
  float* outb = out + (size_t)b * NPTS * NFEAT;
#pragma unroll
  for (int p = 0; p < 4; p++) {
    const int c = p * 16 + (t >> 4);
    const int nq = (t & 15) * 4;
    const float4 v = *(const float4*)&inb[(size_t)c * NPTS + n0 + nq];
    tile[c][nq + 0] = v.x;
    tile[c][nq + 1] = v.y;
    tile[c][nq + 2] = v.z;
    tile[c][nq + 3] = v.w;
  }
  __syncthreads();
#pragma unroll
  for (int p = 0; p < 4; p++) {
    const int n = p * 16 + (t >> 4);
    const int cq = (t & 15) * 4;
    float4 v;
    v.x = tile[cq + 0][n];
    v.y = tile[cq + 1][n];
    v.z = tile[cq + 2][n];
    v.w = tile[cq + 3][n];
    *(float4*)&outb[((size_t)n0 + n) * NFEAT + cq] = v;
  }
}

// ---------------------------------------------------------------------------
// Main: grid-accelerated ball query + group. One wave per query.
// ---------------------------------------------------------------------------
__global__ __launch_bounds__(256) void query_group_grid(
    const float* __restrict__ xyz, const float* __restrict__ new_xyz,
    const float* __restrict__ featT, const float4* __restrict__ cellPts,
    const int* __restrict__ cellStart, float* __restrict__ out) {
  __shared__ int H[4][MAXHIT];

  const int w = threadIdx.x >> 6;
  const int lane = threadIdx.x & 63;
  const int query = blockIdx.x * 4 + w;
  const int b = query / NQ;
  const int j = query % NQ;

  const float* q = new_xyz + ((size_t)b * NQ + j) * 3;
  const float qx = q[0], qy = q[1], qz = q[2];

  const float R2 = (float)(0.1 * 0.1);  // 0x3C23D70A — matches np exactly

  int cx, cy, cz;
  cell3(qx, qy, qz, cx, cy, cz);

  const int* cs = cellStart + b * CSTRIDE;
  const float4* cp = cellPts + (size_t)b * NPTS;

  int count = 0;
#pragma unroll
  for (int dz = -1; dz <= 1; dz++) {
#pragma unroll
    for (int dy = -1; dy <= 1; dy++) {
      const int cyy = cy + dy, czz = cz + dz;
      if (cyy < 0 || cyy > GRID - 1 || czz < 0 || czz > GRID - 1) continue;
      const int rowbase = (czz * GRID + cyy) * GRID;
      const int c0 = rowbase + max(cx - 1, 0);
      const int c1 = rowbase + min(cx + 1, GRID - 1);
      const int s = cs[c0];
      const int e = cs[c1 + 1];
      for (int i = s + lane; i < e + 63; i += 64) {
        // clamp so inactive lanes don't fault; predicate with i<e
        const float4 p = cp[min(i, NPTS - 1)];
        const float dx = __fsub_rn(qx, p.x);
        const float dyf = __fsub_rn(qy, p.y);
        const float dzf = __fsub_rn(qz, p.z);
        const float d2 =
            __fadd_rn(__fadd_rn(__fmul_rn(dx, dx), __fmul_rn(dyf, dyf)),
                      __fmul_rn(dzf, dzf));
        const bool hit = (i < e) && (d2 < R2);
        const unsigned long long m = __ballot(hit);
        if (hit) {
          const int pos = count + prefix_popc(m);
          if (pos < MAXHIT) H[w][pos] = __float_as_int(p.w);
        }
        count += (int)__popcll(m);
      }
    }
  }

  // Overflow fallback (>128 hits): exact sequential ordered scan (first 32).
  if (count > MAXHIT) {
    const float* xb = xyz + (size_t)b * NPTS * 3;
    int cnt2 = 0;
    for (int base = 0; base < NPTS; base += 64) {
      const int i = base + lane;
      const float dx = __fsub_rn(qx, xb[i * 3 + 0]);
      const float dyf = __fsub_rn(qy, xb[i * 3 + 1]);
      const float dzf = __fsub_rn(qz, xb[i * 3 + 2]);
      const float d2 =
          __fadd_rn(__fadd_rn(__fmul_rn(dx, dx), __fmul_rn(dyf, dyf)),
                    __fmul_rn(dzf, dzf));
      const bool hit = d2 < R2;
      const unsigned long long m = __ballot(hit);
      if (hit) {
        const int pos = cnt2 + prefix_popc(m);
        if (pos < NS) H[w][pos] = i;
      }
      cnt2 += (int)__popcll(m);
      if (cnt2 >= NS) break;
    }
    count = min(cnt2, NS);  // already sorted ascending; sort below is a no-op
  }

  const int total = min(count, MAXHIT);

  // Pad unused slots with +inf sentinel.
  for (int s2 = lane; s2 < MAXHIT; s2 += 64)
    if (s2 >= total) H[w][s2] = 0x7fffffff;

  // Bitonic sort 128 ints ascending. 28 passes; barrier count is uniform
  // across all 4 waves of the block (every wave runs this unconditionally).
  for (int k = 2; k <= MAXHIT; k <<= 1) {
    for (int jj = k >> 1; jj > 0; jj >>= 1) {
      __syncthreads();
      const int i = ((lane & ~(jj - 1)) << 1) | (lane & (jj - 1));
      const int ip = i | jj;
      const int a = H[w][i];
      const int bv = H[w][ip];
      const bool up = (i & k) == 0;
      if ((a > bv) == up) {
        H[w][i] = bv;
        H[w][ip] = a;
      }
    }
  }
  __syncthreads();

  // -------- group phase --------
  const int found = min(total, NS);
  const int k2 = lane & 31;
  const int half = lane >> 5;
  int gi = (k2 < found) ? H[w][k2] : ((found > 0) ? H[w][0] : 0);

  const float* xb = xyz + (size_t)b * NPTS * 3;
  const float px = xb[gi * 3 + 0];
  const float py = xb[gi * 3 + 1];
  const float pz = xb[gi * 3 + 2];

  // out[((b*NCH + c)*NQ + j)*NS + k]
  const size_t obase = ((size_t)b * NCH * NQ + j) * (size_t)NS + k2;
  for (int c = half; c < NCH; c += 2) {
    float v;
    if (c < 3) {
      v = (c == 0) ? __fsub_rn(px, qx)
                   : (c == 1) ? __fsub_rn(py, qy) : __fsub_rn(pz, qz);
    } else {
      v = featT[((size_t)b * NPTS + gi) * NFEAT + (c - 3)];
    }
    out[obase + (size_t)c * (NQ * NS)] = v;
  }
}

// ---------------------------------------------------------------------------
// Fallback (small workspace): round-1 kernel, known-correct.
// ---------------------------------------------------------------------------
template <bool TRANS>
__global__ __launch_bounds__(256) void query_group(
    const float* __restrict__ xyz, const float* __restrict__ new_xyz,
    const float* __restrict__ feat, float* __restrict__ out) {
  __shared__ int sidx[4][NS];
  const int w = threadIdx.x >> 6;
  const int lane = threadIdx.x & 63;
  const int query = blockIdx.x * 4 + w;
  const int b = query / NQ;
  const int j = query % NQ;
  const float* q = new_xyz + ((size_t)b * NQ + j) * 3;
  const float qx = q[0], qy = q[1], qz = q[2];
  const float* xb = xyz + (size_t)b * NPTS * 3;
  const float R2 = (float)(0.1 * 0.1);
  int count = 0;
  for (int base = 0; base < NPTS; base += 64) {
    const int i = base + lane;
    const float dx = __fsub_rn(qx, xb[i * 3 + 0]);
    const float dy = __fsub_rn(qy, xb[i * 3 + 1]);
    const float dz = __fsub_rn(qz, xb[i * 3 + 2]);
    const float d2 = __fadd_rn(
        __fadd_rn(__fmul_rn(dx, dx), __fmul_rn(dy, dy)), __fmul_rn(dz, dz));
    const bool hit = d2 < R2;
    const unsigned long long m = __ballot(hit);
    if (hit) {
      const int pos = count + prefix_popc(m);
      if (pos < NS) sidx[w][pos] = i;
    }
    count += (int)__popcll(m);
    if (count >= NS) break;
  }
  const int found = count < NS ? count : NS;
  const int s0 = sidx[w][0];
  const int fill = (found > 0) ? s0 : 0;
  if (lane < NS && lane >= found) sidx[w][lane] = fill;
  const int k = lane & 31;
  const int half = lane >> 5;
  const int gi = sidx[w][k];
  const float px = xb[gi * 3 + 0], py = xb[gi * 3 + 1], pz = xb[gi * 3 + 2];
  const size_t obase = ((size_t)b * NCH * NQ + j) * (size_t)NS + k;
  for (int c = half; c < NCH; c += 2) {
    float v;
    if (c < 3) {
      v = (c == 0) ? __fsub_rn(px, qx)
                   : (c == 1) ? __fsub_rn(py, qy) : __fsub_rn(pz, qz);
    } else {
      if (TRANS)
        v = feat[((size_t)b * NPTS + gi) * NFEAT + (c - 3)];
      else
        v = feat[((size_t)b * NFEAT + (c - 3)) * NPTS + gi];
    }
    out[obase + (size_t)c * (NQ * NS)] = v;
  }
}

extern "C" void kernel_launch(void* const* d_in, const int* in_sizes, int n_in,
                              void* d_out, int out_size, void* d_ws,
                              size_t ws_size, hipStream_t stream) {
  const float* xyz     = (const float*)d_in[0];  // (B, N, 3)
  const float* new_xyz = (const float*)d_in[1];  // (B, NPOINT, 3)
  const float* feat    = (const float*)d_in[2];  // (B, C, N)
  float* out = (float*)d_out;                    // (B, 67, NPOINT, 32)

  // Workspace layout
  const size_t szFeatT  = (size_t)BATCH * NPTS * NFEAT * sizeof(float);  // 16 MB
  const size_t szCells  = (size_t)BATCH * NPTS * sizeof(float4);         // 1 MB
  const size_t szCStart = (size_t)BATCH * CSTRIDE * sizeof(int);
  const size_t szHist   = (size_t)BATCH * NCELL * sizeof(int);
  const size_t need = szFeatT + szCells + szCStart + 2 * szHist;

  const int nblocks = (BATCH * NQ) / 4;

  if (ws_size >= need) {
    char* p = (char*)d_ws;
    float*  featT     = (float*)p;            p += szFeatT;
    float4* cellPts   = (float4*)p;           p += szCells;
    int*    cellStart = (int*)p;              p += szCStart;
    int*    hist      = (int*)p;              p += szHist;
    int*    fill      = (int*)p;              // adjacent to hist

    hipMemsetAsync(hist, 0, 2 * szHist, stream);
    hist_kernel<<<(BATCH * NPTS) / 256, 256, 0, stream>>>(xyz, hist);
    scan_kernel<<<BATCH, 256, 0, stream>>>(hist, cellStart);
    scatter_kernel<<<(BATCH * NPTS) / 256, 256, 0, stream>>>(xyz, cellStart,
                                                             fill, cellPts);
    transpose_feat<<<dim3(NPTS / 64, BATCH), 256, 0, stream>>>(feat, featT);
    query_group_grid<<<nblocks, 256, 0, stream>>>(xyz, new_xyz, featT, cellPts,
                                                  cellStart, out);
  } else if (ws_size >= szFeatT) {
    float* featT = (float*)d_ws;
    dim3 tg(NPTS / 32, NFEAT / 32, BATCH);
    // round-1 transpose layout (32x32) reused via 64x64 kernel grid:
    transpose_feat<<<dim3(NPTS / 64, BATCH), 256, 0, stream>>>(feat, featT);
    query_group<true><<<nblocks, 256, 0, stream>>>(xyz, new_xyz, featT, out);
  } else {
    query_group<false><<<nblocks, 256, 0, stream>>>(xyz, new_xyz, feat, out);
  }
}

// Round 3
// 134.802 us; speedup vs baseline: 1.4237x; 1.1435x over previous
//
#include <hip/hip_runtime.h>

#define BATCH 4
#define NPTS 16384
#define NQ 2048
#define NFEAT 64
#define NS 32
#define NCH 67        // 3 + NFEAT
#define GRID 10       // cell edge 0.1 == radius
#define NCELL 1000
#define CSTRIDE 1024  // per-batch stride for cellStart
#define MAXHIT 128    // hit-list capacity per query (expected ~68 hits)

__device__ __forceinline__ int prefix_popc(unsigned long long m) {
  return (int)__builtin_amdgcn_mbcnt_hi(
      (unsigned)(m >> 32), __builtin_amdgcn_mbcnt_lo((unsigned)m, 0u));
}

__device__ __forceinline__ void cell3(float x, float y, float z, int& cx,
                                      int& cy, int& cz) {
  cx = min(max((int)(x * 10.0f), 0), GRID - 1);
  cy = min(max((int)(y * 10.0f), 0), GRID - 1);
  cz = min(max((int)(z * 10.0f), 0), GRID - 1);
}

// ---------------------------------------------------------------------------
// prep: blocks 0..3 build the per-batch cell grid entirely in LDS
// (hist -> scan -> scatter); blocks 4.. transpose features (B,C,N)->(B,N,C).
// One dispatch replaces memset+hist+scan+scatter+transpose.
// ---------------------------------------------------------------------------
__global__ __launch_bounds__(1024) void prep_kernel(
    const float* __restrict__ xyz, const float* __restrict__ feat,
    float* __restrict__ featT, float4* __restrict__ cellPts,
    int* __restrict__ cellStart) {
  __shared__ int lhist[1024];
  __shared__ int lscan[1024];
  __shared__ int lfill[1024];
  __shared__ float tile[64][65];
  const int tid = threadIdx.x;

  if (blockIdx.x < BATCH) {
    // ----- grid build, one block per batch -----
    const int b = blockIdx.x;
    const float* xb = xyz + (size_t)b * NPTS * 3;
    lhist[tid] = 0;
    lfill[tid] = 0;
    __syncthreads();
#pragma unroll
    for (int c = 0; c < NPTS / 1024; c++) {
      const int i = c * 1024 + tid;
      const float x = xb[i * 3 + 0];
      const float y = xb[i * 3 + 1];
      const float z = xb[i * 3 + 2];
      int cx, cy, cz;
      cell3(x, y, z, cx, cy, cz);
      atomicAdd(&lhist[(cz * GRID + cy) * GRID + cx], 1);
    }
    __syncthreads();
    const int val = lhist[tid];
    lscan[tid] = val;
    __syncthreads();
    for (int d = 1; d < 1024; d <<= 1) {
      const int t2 = (tid >= d) ? lscan[tid - d] : 0;
      __syncthreads();
      lscan[tid] += t2;
      __syncthreads();
    }
    const int excl = lscan[tid] - val;  // exclusive prefix
    if (tid <= NCELL) cellStart[b * CSTRIDE + tid] = excl;  // [NCELL]==NPTS
    lhist[tid] = excl;  // reuse as per-cell start
    __syncthreads();
#pragma unroll
    for (int c = 0; c < NPTS / 1024; c++) {
      const int i = c * 1024 + tid;
      const float x = xb[i * 3 + 0];
      const float y = xb[i * 3 + 1];
      const float z = xb[i * 3 + 2];
      int cx, cy, cz;
      cell3(x, y, z, cx, cy, cz);
      const int cid = (cz * GRID + cy) * GRID + cx;
      const int pos = lhist[cid] + atomicAdd(&lfill[cid], 1);
      cellPts[(size_t)b * NPTS + pos] = make_float4(x, y, z, __int_as_float(i));
    }
  } else {
    // ----- transpose tile, 64x64, 1024 threads (one pass each way) -----
    const int t2 = blockIdx.x - BATCH;
    const int b = t2 >> 8;            // 256 tiles per batch
    const int n0 = (t2 & 255) * 64;
    const float* inb = feat + (size_t)b * NFEAT * NPTS;
    float* outb = featT + (size_t)b * NPTS * NFEAT;
    {
      const int c = tid >> 4;
      const int nq = (tid & 15) * 4;
      const float4 v = *(const float4*)&inb[(size_t)c * NPTS + n0 + nq];
      tile[c][nq + 0] = v.x;
      tile[c][nq + 1] = v.y;
      tile[c][nq + 2] = v.z;
      tile[c][nq + 3] = v.w;
    }
    __syncthreads();
    {
      const int n = tid >> 4;
      const int cq = (tid & 15) * 4;
      float4 v;
      v.x = tile[cq + 0][n];
      v.y = tile[cq + 1][n];
      v.z = tile[cq + 2][n];
      v.w = tile[cq + 3][n];
      *(float4*)&outb[(size_t)(n0 + n) * NFEAT + cq] = v;
    }
  }
}

// ---------------------------------------------------------------------------
// main: grid ball-query + register bitonic sort + staged coalesced group.
// One wave per query, 4 waves per block.
// ---------------------------------------------------------------------------
__global__ __launch_bounds__(256) void qg_main(
    const float* __restrict__ xyz, const float* __restrict__ new_xyz,
    const float* __restrict__ featT, const float4* __restrict__ cellPts,
    const int* __restrict__ cellStart, float* __restrict__ out) {
  __shared__ int H[4][MAXHIT];
  __shared__ float Hx[4][MAXHIT], Hy[4][MAXHIT], Hz[4][MAXHIT];
  __shared__ int S[4][NS];
  __shared__ float F[4][35][33];  // pad 33: ~2-way conflicts only (free)

  const int w = threadIdx.x >> 6;
  const int lane = threadIdx.x & 63;
  const int query = blockIdx.x * 4 + w;
  const int b = query >> 11;  // / NQ
  const int j = query & (NQ - 1);

  const float* q = new_xyz + ((size_t)b * NQ + j) * 3;
  const float qx = q[0], qy = q[1], qz = q[2];

  const float R2 = (float)(0.1 * 0.1);  // 0x3C23D70A — matches np exactly

  int cx, cy, cz;
  cell3(qx, qy, qz, cx, cy, cz);
  const int* cs = cellStart + b * CSTRIDE;
  const float4* cp = cellPts + (size_t)b * NPTS;

  // ---- collect all hits (index + coords) into per-wave LDS lists ----
  int count = 0;
#pragma unroll
  for (int dz = -1; dz <= 1; dz++) {
#pragma unroll
    for (int dy = -1; dy <= 1; dy++) {
      const int cyy = cy + dy, czz = cz + dz;
      if (cyy < 0 || cyy > GRID - 1 || czz < 0 || czz > GRID - 1) continue;
      const int rowbase = (czz * GRID + cyy) * GRID;
      const int s = cs[rowbase + max(cx - 1, 0)];
      const int e = cs[rowbase + min(cx + 1, GRID - 1) + 1];
      for (int i = s + lane; i < e + 63; i += 64) {
        const float4 p = cp[min(i, NPTS - 1)];
        const float dxf = __fsub_rn(qx, p.x);
        const float dyf = __fsub_rn(qy, p.y);
        const float dzf = __fsub_rn(qz, p.z);
        const float d2 =
            __fadd_rn(__fadd_rn(__fmul_rn(dxf, dxf), __fmul_rn(dyf, dyf)),
                      __fmul_rn(dzf, dzf));
        const bool hit = (i < e) && (d2 < R2);
        const unsigned long long m = __ballot(hit);
        if (hit) {
          const int pos = count + prefix_popc(m);
          if (pos < MAXHIT) {
            H[w][pos] = (__float_as_int(p.w) << 7) | pos;  // key: idx|slot
            Hx[w][pos] = p.x;
            Hy[w][pos] = p.y;
            Hz[w][pos] = p.z;
          }
        }
        count += (int)__popcll(m);
      }
    }
  }
  __syncthreads();  // A

  int found;
  if (count <= MAXHIT) {
    // ---- register bitonic sort of 128 packed keys (2 regs/lane) ----
    const int total = count;
    int v0 = (lane < total) ? H[w][lane] : 0x7fffffff;
    int v1 = (lane + 64 < total) ? H[w][lane + 64] : 0x7fffffff;
#pragma unroll
    for (int k = 2; k <= 128; k <<= 1) {
#pragma unroll
      for (int jj = k >> 1; jj > 0; jj >>= 1) {
        if (jj == 64) {  // only when k==128: cross-register, same lane
          const int lo = min(v0, v1), hi = max(v0, v1);
          v0 = lo;
          v1 = hi;
        } else {
          const int o0 = __shfl_xor(v0, jj);
          const int o1 = __shfl_xor(v1, jj);
          const bool lower = (lane & jj) == 0;
          const bool up0 = (lane & k) == 0;          // e0 = lane
          const bool up1 = ((lane + 64) & k) == 0;   // e1 = lane+64
          v0 = (up0 == lower) ? min(v0, o0) : max(v0, o0);
          v1 = (up1 == lower) ? min(v1, o1) : max(v1, o1);
        }
      }
    }
    found = min(total, NS);
    const int fill0 = __shfl(v0, 0);  // smallest key = first hit
    if (lane < NS) S[w][lane] = (lane < found) ? v0 : (found ? fill0 : 0);
  } else {
    // ---- overflow fallback: exact ordered sequential scan (first 32) ----
    const float* xb = xyz + (size_t)b * NPTS * 3;
    int cnt2 = 0;
    for (int base = 0; base < NPTS; base += 64) {
      const int i = base + lane;
      const float px = xb[i * 3 + 0];
      const float py = xb[i * 3 + 1];
      const float pz = xb[i * 3 + 2];
      const float dxf = __fsub_rn(qx, px);
      const float dyf = __fsub_rn(qy, py);
      const float dzf = __fsub_rn(qz, pz);
      const float d2 =
          __fadd_rn(__fadd_rn(__fmul_rn(dxf, dxf), __fmul_rn(dyf, dyf)),
                    __fmul_rn(dzf, dzf));
      const bool hit = d2 < R2;
      const unsigned long long m = __ballot(hit);
      if (hit) {
        const int pos = cnt2 + prefix_popc(m);
        if (pos < NS) {
          S[w][pos] = (i << 7) | pos;
          Hx[w][pos] = px;
          Hy[w][pos] = py;
          Hz[w][pos] = pz;
        }
      }
      cnt2 += (int)__popcll(m);
      if (cnt2 >= NS) break;
    }
    found = min(cnt2, NS);
    if (lane < NS && lane >= found) S[w][lane] = found ? S[w][0] : 0;
  }
  if (found == 0 && lane == 0) {  // no hits -> point 0 per reference
    const float* xb = xyz + (size_t)b * NPTS * 3;
    Hx[w][0] = xb[0];
    Hy[w][0] = xb[1];
    Hz[w][0] = xb[2];
  }
  __syncthreads();  // B

  // ---- group phase: 2 passes of (gather->LDS transpose->float4 store) ----
  const int r8 = lane >> 3;   // row-in-group / channel-in-group
  const int l8 = lane & 7;    // float4 slot / sample-quad
  const float* fb = featT + (size_t)b * NPTS * NFEAT;
  const size_t ob = ((size_t)b * NCH * NQ + j) * (size_t)NS;

  // pass 0: xyz (channels 0..2) + features 0..31 (channels 3..34)
  if (lane < NS) {
    const int packed = S[w][lane];
    const int pos = packed & (MAXHIT - 1);
    F[w][0][lane] = __fsub_rn(Hx[w][pos], qx);
    F[w][1][lane] = __fsub_rn(Hy[w][pos], qy);
    F[w][2][lane] = __fsub_rn(Hz[w][pos], qz);
  }
#pragma unroll
  for (int t = 0; t < 4; t++) {
    const int s = t * 8 + r8;
    const int gi = S[w][s] >> 7;
    const float4 v = *(const float4*)&fb[(size_t)gi * NFEAT + l8 * 4];
    F[w][3 + l8 * 4 + 0][s] = v.x;
    F[w][3 + l8 * 4 + 1][s] = v.y;
    F[w][3 + l8 * 4 + 2][s] = v.z;
    F[w][3 + l8 * 4 + 3][s] = v.w;
  }
  __syncthreads();  // C
#pragma unroll
  for (int c0 = 0; c0 < 35; c0 += 8) {
    const int c = c0 + r8;
    if (c < 35) {
      float4 v;
      v.x = F[w][c][l8 * 4 + 0];
      v.y = F[w][c][l8 * 4 + 1];
      v.z = F[w][c][l8 * 4 + 2];
      v.w = F[w][c][l8 * 4 + 3];
      *(float4*)&out[ob + (size_t)c * (NQ * NS) + l8 * 4] = v;
    }
  }
  __syncthreads();  // D (WAR: pass-1 overwrites F)

  // pass 1: features 32..63 (channels 35..66)
#pragma unroll
  for (int t = 0; t < 4; t++) {
    const int s = t * 8 + r8;
    const int gi = S[w][s] >> 7;
    const float4 v = *(const float4*)&fb[(size_t)gi * NFEAT + 32 + l8 * 4];
    F[w][l8 * 4 + 0][s] = v.x;
    F[w][l8 * 4 + 1][s] = v.y;
    F[w][l8 * 4 + 2][s] = v.z;
    F[w][l8 * 4 + 3][s] = v.w;
  }
  __syncthreads();  // E
#pragma unroll
  for (int c0 = 0; c0 < 32; c0 += 8) {
    const int r = c0 + r8;
    const int c = 35 + r;
    float4 v;
    v.x = F[w][r][l8 * 4 + 0];
    v.y = F[w][r][l8 * 4 + 1];
    v.z = F[w][r][l8 * 4 + 2];
    v.w = F[w][r][l8 * 4 + 3];
    *(float4*)&out[ob + (size_t)c * (NQ * NS) + l8 * 4] = v;
  }
}

// ---------------------------------------------------------------------------
// Fallback for tiny workspace: direct scan kernel (round-1, known-correct).
// ---------------------------------------------------------------------------
__global__ __launch_bounds__(256) void query_group_direct(
    const float* __restrict__ xyz, const float* __restrict__ new_xyz,
    const float* __restrict__ feat, float* __restrict__ out) {
  __shared__ int sidx[4][NS];
  const int w = threadIdx.x >> 6;
  const int lane = threadIdx.x & 63;
  const int query = blockIdx.x * 4 + w;
  const int b = query >> 11;
  const int j = query & (NQ - 1);
  const float* q = new_xyz + ((size_t)b * NQ + j) * 3;
  const float qx = q[0], qy = q[1], qz = q[2];
  const float* xb = xyz + (size_t)b * NPTS * 3;
  const float R2 = (float)(0.1 * 0.1);
  int count = 0;
  for (int base = 0; base < NPTS; base += 64) {
    const int i = base + lane;
    const float dx = __fsub_rn(qx, xb[i * 3 + 0]);
    const float dy = __fsub_rn(qy, xb[i * 3 + 1]);
    const float dz = __fsub_rn(qz, xb[i * 3 + 2]);
    const float d2 = __fadd_rn(
        __fadd_rn(__fmul_rn(dx, dx), __fmul_rn(dy, dy)), __fmul_rn(dz, dz));
    const bool hit = d2 < R2;
    const unsigned long long m = __ballot(hit);
    if (hit) {
      const int pos = count + prefix_popc(m);
      if (pos < NS) sidx[w][pos] = i;
    }
    count += (int)__popcll(m);
    if (count >= NS) break;
  }
  const int found = count < NS ? count : NS;
  const int fill = (found > 0) ? sidx[w][0] : 0;
  if (lane < NS && lane >= found) sidx[w][lane] = fill;
  const int k = lane & 31;
  const int half = lane >> 5;
  const int gi = sidx[w][k];
  const float px = xb[gi * 3 + 0], py = xb[gi * 3 + 1], pz = xb[gi * 3 + 2];
  const size_t obase = ((size_t)b * NCH * NQ + j) * (size_t)NS + k;
  for (int c = half; c < NCH; c += 2) {
    float v;
    if (c < 3) {
      v = (c == 0) ? __fsub_rn(px, qx)
                   : (c == 1) ? __fsub_rn(py, qy) : __fsub_rn(pz, qz);
    } else {
      v = feat[((size_t)b * NFEAT + (c - 3)) * NPTS + gi];
    }
    out[obase + (size_t)c * (NQ * NS)] = v;
  }
}

extern "C" void kernel_launch(void* const* d_in, const int* in_sizes, int n_in,
                              void* d_out, int out_size, void* d_ws,
                              size_t ws_size, hipStream_t stream) {
  const float* xyz     = (const float*)d_in[0];  // (B, N, 3)
  const float* new_xyz = (const float*)d_in[1];  // (B, NPOINT, 3)
  const float* feat    = (const float*)d_in[2];  // (B, C, N)
  float* out = (float*)d_out;                    // (B, 67, NPOINT, 32)

  const size_t szFeatT  = (size_t)BATCH * NPTS * NFEAT * sizeof(float);  // 16MB
  const size_t szCells  = (size_t)BATCH * NPTS * sizeof(float4);         // 1MB
  const size_t szCStart = (size_t)BATCH * CSTRIDE * sizeof(int);
  const size_t need = szFeatT + szCells + szCStart;

  const int nblocks = (BATCH * NQ) / 4;  // one wave per query

  if (ws_size >= need) {
    char* p = (char*)d_ws;
    float*  featT     = (float*)p;  p += szFeatT;
    float4* cellPts   = (float4*)p; p += szCells;
    int*    cellStart = (int*)p;

    prep_kernel<<<BATCH + BATCH * (NPTS / 64), 1024, 0, stream>>>(
        xyz, feat, featT, cellPts, cellStart);
    qg_main<<<nblocks, 256, 0, stream>>>(xyz, new_xyz, featT, cellPts,
                                         cellStart, out);
  } else {
    query_group_direct<<<nblocks, 256, 0, stream>>>(xyz, new_xyz, feat, out);
  }
}